// Round 1
// baseline (31.110 us; speedup 1.0000x reference)
//
#include <hip/hip_runtime.h>
#include <hip/hip_bf16.h>

// h = dot(feat, W1) + b1 decomposes as ph[src] + pg[tgt] + dot(ea, W1x) + dot(u_g, W1u) + b1
// out = leaky(h, 0.1) * W2 + b2

// Precompute per-node partial dot products.
// 16 lanes per row (float4 each), 4 rows per wave, 16 rows per 256-thread block.
__global__ void node_partial_dot(const float* __restrict__ xh,
                                 const float* __restrict__ xg,
                                 const float* __restrict__ W1,
                                 float* __restrict__ ph,
                                 float* __restrict__ pg,
                                 int nh, int ng) {
    int gid  = blockIdx.x * blockDim.x + threadIdx.x;
    int wave = gid >> 6;
    int lane = gid & 63;
    int row  = wave * 4 + (lane >> 4);   // row handled by this 16-lane group
    int q    = lane & 15;                // float4 slot within the 64-float row
    int total = nh + ng;
    if (row >= total) return;

    const float* src;
    const float* w;
    if (row < nh) { src = xh + (size_t)row * 64;        w = W1; }
    else          { src = xg + (size_t)(row - nh) * 64; w = W1 + 64; }

    float4 v  = reinterpret_cast<const float4*>(src)[q];
    float4 wv = reinterpret_cast<const float4*>(w)[q];
    float s = v.x * wv.x + v.y * wv.y + v.z * wv.z + v.w * wv.w;

    // reduce across the 16-lane group
    s += __shfl_xor(s, 1);
    s += __shfl_xor(s, 2);
    s += __shfl_xor(s, 4);
    s += __shfl_xor(s, 8);

    if (q == 0) {
        if (row < nh) ph[row] = s;
        else          pg[row - nh] = s;
    }
}

__global__ void edge_kernel(const int* __restrict__ edge_index,
                            const int* __restrict__ batch_e,
                            const float* __restrict__ edge_attr,
                            const float* __restrict__ u,
                            const float* __restrict__ W1,
                            const float* __restrict__ b1,
                            const float* __restrict__ W2,
                            const float* __restrict__ b2,
                            const float* __restrict__ ph,
                            const float* __restrict__ pg,
                            float* __restrict__ out,
                            int E) {
    int e = blockIdx.x * blockDim.x + threadIdx.x;
    if (e >= E) return;

    int s = edge_index[e];
    int t = edge_index[E + e];
    int g = batch_e[e];

    float h = ph[s] + pg[t] + b1[0];

    // edge_attr dot (8 floats)
    const float4* ea = reinterpret_cast<const float4*>(edge_attr + (size_t)e * 8);
    float4 a0 = ea[0], a1 = ea[1];
    const float* wx = W1 + 128;
    h += a0.x * wx[0] + a0.y * wx[1] + a0.z * wx[2] + a0.w * wx[3]
       + a1.x * wx[4] + a1.y * wx[5] + a1.z * wx[6] + a1.w * wx[7];

    // u dot (16 floats, u table is 4 KB -> L1 resident)
    const float4* ug  = reinterpret_cast<const float4*>(u + (size_t)g * 16);
    const float4* wu4 = reinterpret_cast<const float4*>(W1 + 136);
#pragma unroll
    for (int j = 0; j < 4; ++j) {
        float4 uv = ug[j];
        float4 wv = wu4[j];
        h += uv.x * wv.x + uv.y * wv.y + uv.z * wv.z + uv.w * wv.w;
    }

    h = (h >= 0.0f) ? h : 0.1f * h;
    out[e] = h * W2[0] + b2[0];
}

// Safety fallback if workspace is too small: direct gather per edge (slow but correct).
__global__ void edge_fallback(const int* __restrict__ edge_index,
                              const int* __restrict__ batch_e,
                              const float* __restrict__ xh,
                              const float* __restrict__ xg,
                              const float* __restrict__ edge_attr,
                              const float* __restrict__ u,
                              const float* __restrict__ W1,
                              const float* __restrict__ b1,
                              const float* __restrict__ W2,
                              const float* __restrict__ b2,
                              float* __restrict__ out,
                              int E) {
    int e = blockIdx.x * blockDim.x + threadIdx.x;
    if (e >= E) return;
    int s = edge_index[e];
    int t = edge_index[E + e];
    int g = batch_e[e];
    float h = b1[0];
    const float* hs = xh + (size_t)s * 64;
    const float* gt = xg + (size_t)t * 64;
#pragma unroll 8
    for (int j = 0; j < 64; ++j) h += hs[j] * W1[j];
#pragma unroll 8
    for (int j = 0; j < 64; ++j) h += gt[j] * W1[64 + j];
    const float* ea = edge_attr + (size_t)e * 8;
#pragma unroll
    for (int j = 0; j < 8; ++j) h += ea[j] * W1[128 + j];
    const float* ug = u + (size_t)g * 16;
#pragma unroll
    for (int j = 0; j < 16; ++j) h += ug[j] * W1[136 + j];
    h = (h >= 0.0f) ? h : 0.1f * h;
    out[e] = h * W2[0] + b2[0];
}

extern "C" void kernel_launch(void* const* d_in, const int* in_sizes, int n_in,
                              void* d_out, int out_size, void* d_ws, size_t ws_size,
                              hipStream_t stream) {
    const float* x_h       = (const float*)d_in[0];
    const float* x_g       = (const float*)d_in[1];
    const float* edge_attr = (const float*)d_in[2];
    const float* u         = (const float*)d_in[3];
    const int*   edge_idx  = (const int*)d_in[4];
    const int*   batch_e   = (const int*)d_in[5];
    const float* W1        = (const float*)d_in[6];
    const float* b1        = (const float*)d_in[7];
    const float* W2        = (const float*)d_in[8];
    const float* b2        = (const float*)d_in[9];
    float* out = (float*)d_out;

    const int E  = in_sizes[5];        // N_EDGES
    const int nh = in_sizes[0] / 64;   // N_H_NODES
    const int ng = in_sizes[1] / 64;   // N_G_NODES

    size_t need = (size_t)(nh + ng) * sizeof(float);
    if (ws_size >= need) {
        float* ph = (float*)d_ws;
        float* pg = ph + nh;
        int totalRows = nh + ng;
        int rowsPerBlock = 16;                 // 256 threads = 4 waves x 4 rows
        int nb = (totalRows + rowsPerBlock - 1) / rowsPerBlock;
        node_partial_dot<<<nb, 256, 0, stream>>>(x_h, x_g, W1, ph, pg, nh, ng);

        int eb = (E + 255) / 256;
        edge_kernel<<<eb, 256, 0, stream>>>(edge_idx, batch_e, edge_attr, u,
                                            W1, b1, W2, b2, ph, pg, out, E);
    } else {
        int eb = (E + 255) / 256;
        edge_fallback<<<eb, 256, 0, stream>>>(edge_idx, batch_e, x_h, x_g, edge_attr, u,
                                              W1, b1, W2, b2, out, E);
    }
}